// Round 3
// baseline (110.461 us; speedup 1.0000x reference)
//
#include <hip/hip_runtime.h>
#include <math.h>

// Problem constants (fixed by setup_inputs): bsz=16, sent_len=512 -> N=8192 rows,
// cont_dim D=768, mp_dim P=20. fp32 in, fp32 out.
static constexpr int D_DIM = 768;
static constexpr int NP    = 20;
static constexpr int NROWS = 8192;
static constexpr int RPB   = 8;              // rows per block
static constexpr int BLOCKS = NROWS / RPB;   // 1024

// One stage of a DPP reduction: x += dpp_move(x). Pure VALU — no LDS pipe.
template <int CTRL>
__device__ __forceinline__ float dpp_add(float x) {
  int t = __builtin_amdgcn_update_dpp(0, __float_as_int(x), CTRL, 0xF, 0xF, true);
  return x + __int_as_float(t);
}

// Full 64-lane sum; result valid in lane 63 only. row_shr:1/2/4/8 then
// row_bcast:15 (0x142), row_bcast:31 (0x143); bound_ctrl=1 zeroes OOB sources.
__device__ __forceinline__ float wave_sum63(float x) {
  x = dpp_add<0x111>(x);
  x = dpp_add<0x112>(x);
  x = dpp_add<0x114>(x);
  x = dpp_add<0x118>(x);
  x = dpp_add<0x142>(x);
  x = dpp_add<0x143>(x);
  return x;
}

// Async global->LDS DMA, 16 B per lane. LDS dest semantics: wave-uniform base +
// lane*16 (m104/m108) — our per-lane dest (base + tid*16) satisfies this, and
// the LDS layout is fully contiguous (no padding) to match.
__device__ __forceinline__ void async_copy16(const void* g, void* l) {
  __builtin_amdgcn_global_load_lds(
      (const __attribute__((address_space(1))) unsigned int*)(uintptr_t)g,
      (__attribute__((address_space(3))) unsigned int*)(uint32_t)(uintptr_t)l,
      16, 0, 0);
}

__global__ __launch_bounds__(256, 3) void atte_cos_kernel(
    const float* __restrict__ repres,
    const float* __restrict__ max_att,
    const float* __restrict__ weight,
    float* __restrict__ out)
{
  const int tid  = threadIdx.x;
  const int wave = tid >> 6;      // 0..3 -> perspective chunk (5 p each)
  const int lane = tid & 63;
  const int part = lane >> 4;     // 0..3
  const int sub  = lane & 15;     // 0..15
  // lane covers d = d0 + {0..3} + k*64, k=0..2 (12 elements). Per 16-lane
  // quarter the float4 reads cover a contiguous 256 B block -> conflict-free.
  const int d0    = part * 192 + sub * 4;
  const int pbase = wave * 5;

  // [0, RPB*D)          : repres rows (contiguous, row-major)
  // [RPB*D, 2*RPB*D)    : max_att rows
  __shared__ float lds[2 * RPB * D_DIM];   // 48 KB -> 3 blocks/CU

  const int row0 = blockIdx.x * RPB;

  // Stage 8 rows of r and m (24 KB each): 6 chunks of 4 KB per matrix.
  // Each chunk is one global_load_lds per thread (256 x 16 B = 4 KB).
  {
    const char* gr = (const char*)(repres  + (size_t)row0 * D_DIM);
    const char* gm = (const char*)(max_att + (size_t)row0 * D_DIM);
    char* lr = (char*)&lds[0];
    char* lm = (char*)&lds[RPB * D_DIM];
#pragma unroll
    for (int c = 0; c < 6; ++c)
      async_copy16(gr + c * 4096 + tid * 16, lr + c * 4096 + tid * 16);
#pragma unroll
    for (int c = 0; c < 6; ++c)
      async_copy16(gm + c * 4096 + tid * 16, lm + c * 4096 + tid * 16);
  }

  // w^2 fragments in registers: 5 p x 3 chunks x float4 = 60 VGPRs. Issued
  // while the DMA is in flight (independent of LDS).
  float4 w2r[5][3];
#pragma unroll
  for (int p = 0; p < 5; ++p) {
#pragma unroll
    for (int k = 0; k < 3; ++k) {
      float4 w4 = *(const float4*)(weight + (pbase + p) * D_DIM + d0 + k * 64);
      w4.x *= w4.x; w4.y *= w4.y; w4.z *= w4.z; w4.w *= w4.w;
      w2r[p][k] = w4;
    }
  }

  __syncthreads();  // drains vmcnt(0) -> staged tile visible to all waves

  for (int t = 0; t < RPB; ++t) {
    const float* lr = &lds[t * D_DIM + d0];
    const float* lm = &lds[RPB * D_DIM + t * D_DIM + d0];

    float4 r4[3], m4[3];
#pragma unroll
    for (int k = 0; k < 3; ++k) {
      r4[k] = *(const float4*)(lr + k * 64);
      m4[k] = *(const float4*)(lm + k * 64);
    }

    // acc[p*3+q]: q=0 dot, q=1 ||r w||^2, q=2 ||m w||^2
    float acc[15];
#pragma unroll
    for (int v = 0; v < 15; ++v) acc[v] = 0.0f;

#pragma unroll
    for (int k = 0; k < 3; ++k) {
      float rmv[4], rrv[4], mmv[4];
      const float* rv_ = (const float*)&r4[k];
      const float* mv_ = (const float*)&m4[k];
#pragma unroll
      for (int c = 0; c < 4; ++c) {
        const float rv = rv_[c], mv = mv_[c];
        rmv[c] = rv * mv; rrv[c] = rv * rv; mmv[c] = mv * mv;
      }
#pragma unroll
      for (int p = 0; p < 5; ++p) {
        const float* w = (const float*)&w2r[p][k];
#pragma unroll
        for (int c = 0; c < 4; ++c) {
          acc[p*3+0] = fmaf(rmv[c], w[c], acc[p*3+0]);
          acc[p*3+1] = fmaf(rrv[c], w[c], acc[p*3+1]);
          acc[p*3+2] = fmaf(mmv[c], w[c], acc[p*3+2]);
        }
      }
    }

    // All-VALU 64-lane reduction; 15 independent 6-stage DPP chains interleave.
#pragma unroll
    for (int v = 0; v < 15; ++v) acc[v] = wave_sum63(acc[v]);

    if (lane == 63) {
#pragma unroll
      for (int p = 0; p < 5; ++p) {
        const float dot = acc[p*3+0];
        const float n1  = fmaxf(sqrtf(acc[p*3+1]), 1e-8f);
        const float n2  = fmaxf(sqrtf(acc[p*3+2]), 1e-8f);
        out[(size_t)(row0 + t) * NP + pbase + p] = dot / (n1 * n2);
      }
    }
  }
}

extern "C" void kernel_launch(void* const* d_in, const int* in_sizes, int n_in,
                              void* d_out, int out_size, void* d_ws, size_t ws_size,
                              hipStream_t stream) {
  const float* repres  = (const float*)d_in[0];
  const float* max_att = (const float*)d_in[1];
  const float* weight  = (const float*)d_in[2];
  float* out = (float*)d_out;

  atte_cos_kernel<<<BLOCKS, 256, 0, stream>>>(repres, max_att, weight, out);
}

// Round 4
// 109.183 us; speedup vs baseline: 1.0117x; 1.0117x over previous
//
#include <hip/hip_runtime.h>
#include <math.h>

// Problem constants (fixed by setup_inputs): bsz=16, sent_len=512 -> N=8192 rows,
// cont_dim D=768, mp_dim P=20. fp32 in, fp32 out.
static constexpr int D_DIM = 768;
static constexpr int NP    = 20;
static constexpr int NROWS = 8192;
static constexpr int RPB   = 8;              // rows per block
static constexpr int BLOCKS = NROWS / RPB;   // 1024

// Compiler barrier: forces x to live in a VGPR and prevents the scheduler from
// sinking/rematerializing the computation that produced it. (R3 post-mortem:
// without this the allocator dropped to 68 VGPRs and re-loaded w^2 per row.)
#define PIN_V(x) asm volatile("" : "+v"(x))

// One stage of a DPP reduction: x += dpp_move(x). Pure VALU — no LDS pipe.
template <int CTRL>
__device__ __forceinline__ float dpp_add(float x) {
  int t = __builtin_amdgcn_update_dpp(0, __float_as_int(x), CTRL, 0xF, 0xF, true);
  return x + __int_as_float(t);
}

// Full 64-lane sum; result valid in lane 63 only. row_shr:1/2/4/8 then
// row_bcast:15 (0x142), row_bcast:31 (0x143); bound_ctrl=1 zeroes OOB sources.
__device__ __forceinline__ float wave_sum63(float x) {
  x = dpp_add<0x111>(x);
  x = dpp_add<0x112>(x);
  x = dpp_add<0x114>(x);
  x = dpp_add<0x118>(x);
  x = dpp_add<0x142>(x);
  x = dpp_add<0x143>(x);
  return x;
}

// Async global->LDS DMA, 16 B per lane (wave-uniform base + lane*16 dest).
__device__ __forceinline__ void async_copy16(const void* g, void* l) {
  __builtin_amdgcn_global_load_lds(
      (const __attribute__((address_space(1))) unsigned int*)(uintptr_t)g,
      (__attribute__((address_space(3))) unsigned int*)(uint32_t)(uintptr_t)l,
      16, 0, 0);
}

__global__ __launch_bounds__(256) void atte_cos_kernel(
    const float* __restrict__ repres,
    const float* __restrict__ max_att,
    const float* __restrict__ weight,
    float* __restrict__ out)
{
  const int tid  = threadIdx.x;
  const int wave = tid >> 6;      // 0..3 -> perspective chunk (5 p each)
  const int lane = tid & 63;
  const int part = lane >> 4;     // 0..3
  const int sub  = lane & 15;     // 0..15
  // lane covers d = d0 + {0..3} + k*64, k=0..2 (12 elements). Per 16-lane
  // quarter the float4 reads cover a contiguous 256 B block -> conflict-free.
  const int d0    = part * 192 + sub * 4;
  const int pbase = wave * 5;

  // [0, RPB*D): repres rows; [RPB*D, 2*RPB*D): max_att rows. 48 KB.
  __shared__ float lds[2 * RPB * D_DIM];

  const int row0 = blockIdx.x * RPB;

  // Stage 8 rows of r and m (24 KB each): 6 chunks of 4 KB per matrix,
  // one global_load_lds_dwordx4 per thread per chunk.
  {
    const char* gr = (const char*)(repres  + (size_t)row0 * D_DIM);
    const char* gm = (const char*)(max_att + (size_t)row0 * D_DIM);
    char* lr = (char*)&lds[0];
    char* lm = (char*)&lds[RPB * D_DIM];
#pragma unroll
    for (int c = 0; c < 6; ++c)
      async_copy16(gr + c * 4096 + tid * 16, lr + c * 4096 + tid * 16);
#pragma unroll
    for (int c = 0; c < 6; ++c)
      async_copy16(gm + c * 4096 + tid * 16, lm + c * 4096 + tid * 16);
  }

  // w^2 fragments in registers: 5 p x 3 chunks x float4 = 60 VGPRs, loaded and
  // squared ONCE, then pinned so they stay register-resident across the loop.
  float4 w2r[5][3];
#pragma unroll
  for (int p = 0; p < 5; ++p) {
#pragma unroll
    for (int k = 0; k < 3; ++k) {
      float4 w4 = *(const float4*)(weight + (pbase + p) * D_DIM + d0 + k * 64);
      w4.x *= w4.x; w4.y *= w4.y; w4.z *= w4.z; w4.w *= w4.w;
      w2r[p][k] = w4;
    }
  }
#pragma unroll
  for (int p = 0; p < 5; ++p) {
#pragma unroll
    for (int k = 0; k < 3; ++k) {
      PIN_V(w2r[p][k].x); PIN_V(w2r[p][k].y);
      PIN_V(w2r[p][k].z); PIN_V(w2r[p][k].w);
    }
  }

  __syncthreads();  // drains vmcnt(0) -> staged tile visible to all waves

  for (int t = 0; t < RPB; ++t) {
    const float* lr = &lds[t * D_DIM + d0];
    const float* lm = &lds[RPB * D_DIM + t * D_DIM + d0];

    float4 r4[3], m4[3];
#pragma unroll
    for (int k = 0; k < 3; ++k) {
      r4[k] = *(const float4*)(lr + k * 64);
      m4[k] = *(const float4*)(lm + k * 64);
    }

    // acc[p*3+q]: q=0 dot, q=1 ||r w||^2, q=2 ||m w||^2. k=0 initializes via
    // mul (no zero-init v_movs), k=1..2 accumulate via fma.
    float acc[15];
#pragma unroll
    for (int k = 0; k < 3; ++k) {
      float rmv[4], rrv[4], mmv[4];
      const float* rv_ = (const float*)&r4[k];
      const float* mv_ = (const float*)&m4[k];
#pragma unroll
      for (int c = 0; c < 4; ++c) {
        const float rv = rv_[c], mv = mv_[c];
        rmv[c] = rv * mv; rrv[c] = rv * rv; mmv[c] = mv * mv;
      }
#pragma unroll
      for (int p = 0; p < 5; ++p) {
        const float* w = (const float*)&w2r[p][k];
        if (k == 0) {
          acc[p*3+0] = rmv[0] * w[0];
          acc[p*3+1] = rrv[0] * w[0];
          acc[p*3+2] = mmv[0] * w[0];
#pragma unroll
          for (int c = 1; c < 4; ++c) {
            acc[p*3+0] = fmaf(rmv[c], w[c], acc[p*3+0]);
            acc[p*3+1] = fmaf(rrv[c], w[c], acc[p*3+1]);
            acc[p*3+2] = fmaf(mmv[c], w[c], acc[p*3+2]);
          }
        } else {
#pragma unroll
          for (int c = 0; c < 4; ++c) {
            acc[p*3+0] = fmaf(rmv[c], w[c], acc[p*3+0]);
            acc[p*3+1] = fmaf(rrv[c], w[c], acc[p*3+1]);
            acc[p*3+2] = fmaf(mmv[c], w[c], acc[p*3+2]);
          }
        }
      }
    }

    // All-VALU 64-lane reduction; 15 independent 6-stage DPP chains interleave.
#pragma unroll
    for (int v = 0; v < 15; ++v) acc[v] = wave_sum63(acc[v]);

    if (lane == 63) {
#pragma unroll
      for (int p = 0; p < 5; ++p) {
        const float dot = acc[p*3+0];
        const float n1  = fmaxf(sqrtf(acc[p*3+1]), 1e-8f);
        const float n2  = fmaxf(sqrtf(acc[p*3+2]), 1e-8f);
        out[(size_t)(row0 + t) * NP + pbase + p] = dot / (n1 * n2);
      }
    }
  }
}

extern "C" void kernel_launch(void* const* d_in, const int* in_sizes, int n_in,
                              void* d_out, int out_size, void* d_ws, size_t ws_size,
                              hipStream_t stream) {
  const float* repres  = (const float*)d_in[0];
  const float* max_att = (const float*)d_in[1];
  const float* weight  = (const float*)d_in[2];
  float* out = (float*)d_out;

  atte_cos_kernel<<<BLOCKS, 256, 0, stream>>>(repres, max_att, weight, out);
}

// Round 5
// 107.940 us; speedup vs baseline: 1.0234x; 1.0115x over previous
//
#include <hip/hip_runtime.h>
#include <math.h>

// Problem constants (fixed by setup_inputs): bsz=16, sent_len=512 -> N=8192 rows,
// cont_dim D=768, mp_dim P=20. fp32 in, fp32 out.
static constexpr int D_DIM = 768;
static constexpr int NP    = 20;
static constexpr int NROWS = 8192;
static constexpr int RPB   = 8;              // rows per block
static constexpr int BLOCKS = NROWS / RPB;   // 1024

typedef float v2f __attribute__((ext_vector_type(2)));

// Packed fp32 math (VOP3P): 2 FMAs per issue slot. The compiler never emits
// v_pk_fma_f32 from scalar fmaf — this is how fp32 reaches 157 TF on CDNA4.
// R2/R3 post-mortem: identical ~42us with different memory structures => the
// VALU issue volume of the scalar loop was the bottleneck; this halves it.
__device__ __forceinline__ void pk_mul(v2f& d, v2f a, v2f b) {
  asm("v_pk_mul_f32 %0, %1, %2" : "=v"(d) : "v"(a), "v"(b));
}
__device__ __forceinline__ void pk_fma(v2f& d, v2f a, v2f b) {
  asm("v_pk_fma_f32 %0, %1, %2, %0" : "+v"(d) : "v"(a), "v"(b));
}

// One stage of a DPP reduction: x += dpp_move(x). Pure VALU — no LDS pipe.
template <int CTRL>
__device__ __forceinline__ float dpp_add(float x) {
  int t = __builtin_amdgcn_update_dpp(0, __float_as_int(x), CTRL, 0xF, 0xF, true);
  return x + __int_as_float(t);
}

// Full 64-lane sum; result valid in lane 63 only. row_shr:1/2/4/8 then
// row_bcast:15 (0x142), row_bcast:31 (0x143); bound_ctrl=1 zeroes OOB sources.
__device__ __forceinline__ float wave_sum63(float x) {
  x = dpp_add<0x111>(x);
  x = dpp_add<0x112>(x);
  x = dpp_add<0x114>(x);
  x = dpp_add<0x118>(x);
  x = dpp_add<0x142>(x);
  x = dpp_add<0x143>(x);
  return x;
}

// Async global->LDS DMA, 16 B per lane (wave-uniform base + lane*16 dest).
__device__ __forceinline__ void async_copy16(const void* g, void* l) {
  __builtin_amdgcn_global_load_lds(
      (const __attribute__((address_space(1))) unsigned int*)(uintptr_t)g,
      (__attribute__((address_space(3))) unsigned int*)(uint32_t)(uintptr_t)l,
      16, 0, 0);
}

__global__ __launch_bounds__(256) void atte_cos_kernel(
    const float* __restrict__ repres,
    const float* __restrict__ max_att,
    const float* __restrict__ weight,
    float* __restrict__ out)
{
  const int tid  = threadIdx.x;
  const int wave = tid >> 6;      // 0..3 -> perspective chunk (5 p each)
  const int lane = tid & 63;
  const int part = lane >> 4;     // 0..3
  const int sub  = lane & 15;     // 0..15
  // lane covers d = d0 + {0..3} + k*64, k=0..2 (12 elements). Per 16-lane
  // quarter the float4 reads cover a contiguous 256 B block -> conflict-free.
  const int d0    = part * 192 + sub * 4;
  const int pbase = wave * 5;

  // [0, RPB*D): repres rows; [RPB*D, 2*RPB*D): max_att rows. 48 KB -> 3 blk/CU.
  __shared__ float lds[2 * RPB * D_DIM];

  const int row0 = blockIdx.x * RPB;

  // Stage 8 rows of r and m (24 KB each): 6 chunks of 4 KB per matrix,
  // one global_load_lds_dwordx4 per thread per chunk.
  {
    const char* gr = (const char*)(repres  + (size_t)row0 * D_DIM);
    const char* gm = (const char*)(max_att + (size_t)row0 * D_DIM);
    char* lr = (char*)&lds[0];
    char* lm = (char*)&lds[RPB * D_DIM];
#pragma unroll
    for (int c = 0; c < 6; ++c)
      async_copy16(gr + c * 4096 + tid * 16, lr + c * 4096 + tid * 16);
#pragma unroll
    for (int c = 0; c < 6; ++c)
      async_copy16(gm + c * 4096 + tid * 16, lm + c * 4096 + tid * 16);
  }

  // w^2 as 30 float2 pairs (60 VGPRs), loaded+squared once while DMA is in
  // flight. Used as direct register operands of the pk_fma asm below, so the
  // compiler cannot sink or rematerialize them.
  v2f w2r[5][6];   // [p][pair j], pair j covers d = d0 + (j>>1)*64 + (j&1)*2
#pragma unroll
  for (int p = 0; p < 5; ++p) {
#pragma unroll
    for (int k = 0; k < 3; ++k) {
      float4 w4 = *(const float4*)(weight + (pbase + p) * D_DIM + d0 + k * 64);
      v2f lo = {w4.x, w4.y}, hi = {w4.z, w4.w};
      pk_mul(w2r[p][2*k+0], lo, lo);
      pk_mul(w2r[p][2*k+1], hi, hi);
    }
  }

  __syncthreads();  // drains vmcnt(0) -> staged tile visible to all waves

  for (int t = 0; t < RPB; ++t) {
    const float* lr = &lds[t * D_DIM + d0];
    const float* lm = &lds[RPB * D_DIM + t * D_DIM + d0];

    v2f r2[6], m2[6];
#pragma unroll
    for (int k = 0; k < 3; ++k) {
      float4 a = *(const float4*)(lr + k * 64);
      float4 b = *(const float4*)(lm + k * 64);
      r2[2*k+0] = (v2f){a.x, a.y}; r2[2*k+1] = (v2f){a.z, a.w};
      m2[2*k+0] = (v2f){b.x, b.y}; m2[2*k+1] = (v2f){b.z, b.w};
    }

    // acc2[p*3+q]: packed partials. q=0 dot, q=1 ||r w||^2, q=2 ||m w||^2.
    // j=0 initializes via pk_mul (no zero-init), j=1..5 accumulate via pk_fma.
    v2f acc2[15];
#pragma unroll
    for (int j = 0; j < 6; ++j) {
      v2f rm, rr, mm;
      pk_mul(rm, r2[j], m2[j]);
      pk_mul(rr, r2[j], r2[j]);
      pk_mul(mm, m2[j], m2[j]);
#pragma unroll
      for (int p = 0; p < 5; ++p) {
        if (j == 0) {
          pk_mul(acc2[p*3+0], rm, w2r[p][0]);
          pk_mul(acc2[p*3+1], rr, w2r[p][0]);
          pk_mul(acc2[p*3+2], mm, w2r[p][0]);
        } else {
          pk_fma(acc2[p*3+0], rm, w2r[p][j]);
          pk_fma(acc2[p*3+1], rr, w2r[p][j]);
          pk_fma(acc2[p*3+2], mm, w2r[p][j]);
        }
      }
    }

    // Fold packed halves, then all-VALU 64-lane reduction (15 independent
    // 6-stage DPP chains interleave back-to-back).
    float acc[15];
#pragma unroll
    for (int v = 0; v < 15; ++v) acc[v] = acc2[v].x + acc2[v].y;
#pragma unroll
    for (int v = 0; v < 15; ++v) acc[v] = wave_sum63(acc[v]);

    if (lane == 63) {
#pragma unroll
      for (int p = 0; p < 5; ++p) {
        const float dot = acc[p*3+0];
        const float n1  = fmaxf(sqrtf(acc[p*3+1]), 1e-8f);
        const float n2  = fmaxf(sqrtf(acc[p*3+2]), 1e-8f);
        out[(size_t)(row0 + t) * NP + pbase + p] = dot / (n1 * n2);
      }
    }
  }
}

extern "C" void kernel_launch(void* const* d_in, const int* in_sizes, int n_in,
                              void* d_out, int out_size, void* d_ws, size_t ws_size,
                              hipStream_t stream) {
  const float* repres  = (const float*)d_in[0];
  const float* max_att = (const float*)d_in[1];
  const float* weight  = (const float*)d_in[2];
  float* out = (float*)d_out;

  atte_cos_kernel<<<BLOCKS, 256, 0, stream>>>(repres, max_att, weight, out);
}

// Round 6
// 89.338 us; speedup vs baseline: 1.2364x; 1.2082x over previous
//
#include <hip/hip_runtime.h>
#include <math.h>
#include <stdint.h>

// Problem constants: bsz=16, sent_len=512 -> N=8192 rows, D=768, P=20. fp32 io.
static constexpr int D_DIM   = 768;
static constexpr int NP      = 20;
static constexpr int NROWS   = 8192;
static constexpr int ROWS_PB = 16;                 // M-tile per block
static constexpr int BLOCKS  = NROWS / ROWS_PB;    // 512 (2 blocks/CU, one generation)
static constexpr int KW      = 192;                // split-K: k-range per wave
static constexpr int KSLICE  = 32;                 // one MFMA k-step per slice
static constexpr int NSLICES = KW / KSLICE;        // 6

typedef short  short8  __attribute__((ext_vector_type(8)));   // 8 bf16 (4 VGPRs)
typedef float  float4v __attribute__((ext_vector_type(4)));   // MFMA C/D

// ---- LDS map (bytes). A: wave-private double-buffered slices. B: w^2 bf16. ----
static constexpr int A_WAVE = 8192;     // per wave: 2 bufs x (r 2048 + m 2048)
static constexpr int A_BUF  = 4096;
static constexpr int A_MAT  = 2048;     // 16 rows x 32 floats
static constexpr int B_OFF  = 32768;
static constexpr int B_CSTR = 776 * 2;  // col stride: 768 + 8 pad bf16 (4-way-free banks)
static constexpr int LDS_SZ = B_OFF + NP * B_CSTR;  // 63808 < 64K -> 2 blocks/CU

// Async global->LDS DMA, 16 B/lane (dest = wave-uniform base + lane*16).
__device__ __forceinline__ void async_copy16(const void* g, void* l) {
  __builtin_amdgcn_global_load_lds(
      (const __attribute__((address_space(1))) unsigned int*)(uintptr_t)g,
      (__attribute__((address_space(3))) unsigned int*)(uint32_t)(uintptr_t)l,
      16, 0, 0);
}

__device__ __forceinline__ unsigned short bf16_rne(float x) {
  unsigned u = __float_as_uint(x);
  u += 0x7FFFu + ((u >> 16) & 1u);
  return (unsigned short)(u >> 16);
}
__device__ __forceinline__ float bf16f(unsigned short h) {
  return __uint_as_float(((unsigned)h) << 16);
}

__global__ __launch_bounds__(256) void atte_cos_mfma(
    const float* __restrict__ repres,
    const float* __restrict__ max_att,
    const float* __restrict__ weight,
    float* __restrict__ out)
{
  const int tid  = threadIdx.x;
  const int wave = tid >> 6;
  const int lane = tid & 63;
  const int row0 = blockIdx.x * ROWS_PB;
  const int k0   = wave * KW;          // this wave's K range
  const int part = lane >> 4;          // 0..3 -> k-offset part*8 in MFMA frags
  const int mrow = lane & 15;          // A row within tile / C col index

  __shared__ __align__(16) char smem[LDS_SZ];
  char* a_base = smem + wave * A_WAVE;

  // Stage slice s (32 k) of this wave's range into buffer b. Rows are stored
  // 128 B each with 16-B granules rotated by 2*(row&3) so that A-fragment
  // reads (16 rows, stride 128 B) hit 4 bank groups instead of 1 (16-way->4-way).
  // Global side of the DMA is an arbitrary per-lane gather; LDS side is
  // lane-contiguous as required.
  auto stage = [&](int s, int b) {
#pragma unroll
    for (int j = 0; j < 2; ++j) {
      const int slot = j * 64 + lane;          // 0..127 = row*8 + granule
      const int row  = slot >> 3;
      const int gp   = slot & 7;               // physical granule in row
      const int gl   = (gp - 2 * (row & 3)) & 7;  // logical granule (unrotate)
      const float* gr = repres  + (size_t)(row0 + row) * D_DIM + k0 + s * KSLICE + gl * 4;
      const float* gm = max_att + (size_t)(row0 + row) * D_DIM + k0 + s * KSLICE + gl * 4;
      char* la = a_base + b * A_BUF + slot * 16;
      async_copy16(gr, la);
      async_copy16(gm, la + A_MAT);
    }
  };

  stage(0, 0);
  stage(1, 1);

  // B staging: w^2 -> bf16, layout [col][k] with padded stride (shared by all
  // waves; one-time). 768 = 3*256 so k = j*256+tid needs no div.
  for (int col = 0; col < NP; ++col) {
#pragma unroll
    for (int j = 0; j < 3; ++j) {
      const int k = j * 256 + tid;
      const float wv = weight[col * D_DIM + k];
      *(unsigned short*)(smem + B_OFF + col * B_CSTR + k * 2) = bf16_rne(wv * wv);
    }
  }

  __syncthreads();  // B visible to all waves; also drains slices 0,1 (vmcnt 0)

  // A-fragment read offset: row mrow, logical floats part*8..+7 -> physical
  // offset rotated by 8*(mrow&3) floats (granule-aligned, never wraps).
  const int a_off = mrow * 128 + (((part + (mrow & 3)) & 3) * 32);
  // B fragments: B[k0+s*32+part*8 + j][col], contiguous 16 B along k.
  const char* b0p = smem + B_OFF + (lane & 15) * B_CSTR + (k0 + part * 8) * 2;
  const int c1col = min(16 + (lane & 15), NP - 1);   // cols 20..31: junk, unstored
  const char* b1p = smem + B_OFF + c1col * B_CSTR + (k0 + part * 8) * 2;

  float4v acc[6] = {};  // [q*2 + ct]; q: 0=dot 1=||rw||^2 2=||mw||^2

#pragma unroll
  for (int s = 0; s < NSLICES; ++s) {
    // Slice s's 4 DMAs done (<=4 outstanding = prefetch of s+1 stays in flight).
    __builtin_amdgcn_s_waitcnt(0x0F74);  // vmcnt(4), exp/lgkm no-wait
    const char* ab = a_base + (s & 1) * A_BUF;

    float rv[8], mv[8];
    *(float4*)&rv[0] = *(const float4*)(ab + a_off);
    *(float4*)&rv[4] = *(const float4*)(ab + a_off + 16);
    *(float4*)&mv[0] = *(const float4*)(ab + A_MAT + a_off);
    *(float4*)&mv[4] = *(const float4*)(ab + A_MAT + a_off + 16);

    // Products in fp32; dot gets hi+lo bf16 split (error 2^-17), norms hi-only
    // (positive terms -> bf16 noise averages to ~1e-5 relative).
    short8 a0h, a0l, a1h, a2h;
#pragma unroll
    for (int j = 0; j < 8; ++j) {
      const float pm = rv[j] * mv[j];
      const float pr = rv[j] * rv[j];
      const float pq = mv[j] * mv[j];
      const unsigned short h = bf16_rne(pm);
      a0h[j] = (short)h;
      a0l[j] = (short)bf16_rne(pm - bf16f(h));
      a1h[j] = (short)bf16_rne(pr);
      a2h[j] = (short)bf16_rne(pq);
    }

    const short8 b0 = *(const short8*)(b0p + s * 64);
    const short8 b1 = *(const short8*)(b1p + s * 64);

    acc[0] = __builtin_amdgcn_mfma_f32_16x16x32_bf16(a0h, b0, acc[0], 0, 0, 0);
    acc[0] = __builtin_amdgcn_mfma_f32_16x16x32_bf16(a0l, b0, acc[0], 0, 0, 0);
    acc[1] = __builtin_amdgcn_mfma_f32_16x16x32_bf16(a0h, b1, acc[1], 0, 0, 0);
    acc[1] = __builtin_amdgcn_mfma_f32_16x16x32_bf16(a0l, b1, acc[1], 0, 0, 0);
    acc[2] = __builtin_amdgcn_mfma_f32_16x16x32_bf16(a1h, b0, acc[2], 0, 0, 0);
    acc[3] = __builtin_amdgcn_mfma_f32_16x16x32_bf16(a1h, b1, acc[3], 0, 0, 0);
    acc[4] = __builtin_amdgcn_mfma_f32_16x16x32_bf16(a2h, b0, acc[4], 0, 0, 0);
    acc[5] = __builtin_amdgcn_mfma_f32_16x16x32_bf16(a2h, b1, acc[5], 0, 0, 0);

    if (s + 2 < NSLICES) {
      // Drain our ds_reads before the DMA overwrites this buffer.
      __builtin_amdgcn_s_waitcnt(0xC07F);  // lgkmcnt(0), vm no-wait
      stage(s + 2, s & 1);
    }
  }

  // ---- cross-wave K reduction (A region is dead; reuse as scratch) ----
  __syncthreads();  // all waves done computing before anyone scribbles scratch
#pragma unroll
  for (int qc = 0; qc < 6; ++qc)
    *(float4v*)(smem + ((qc * 4 + wave) * 64 + lane) * 16) = acc[qc];
  __syncthreads();

  if (wave < 2) {                // wave = column-tile; same (row,col)->lane map
    const int ct = wave;
    float4v c0 = {}, c1 = {}, c2 = {};
#pragma unroll
    for (int wv = 0; wv < 4; ++wv) {
      c0 += *(const float4v*)(smem + (((0 * 2 + ct) * 4 + wv) * 64 + lane) * 16);
      c1 += *(const float4v*)(smem + (((1 * 2 + ct) * 4 + wv) * 64 + lane) * 16);
      c2 += *(const float4v*)(smem + (((2 * 2 + ct) * 4 + wv) * 64 + lane) * 16);
    }
    const int col = ct * 16 + (lane & 15);
    if (col < NP) {
      const int rbase = row0 + (lane >> 4) * 4;  // C row = (lane>>4)*4 + reg
#pragma unroll
      for (int r = 0; r < 4; ++r) {
        const float n1 = fmaxf(sqrtf(c1[r]), 1e-8f);
        const float n2 = fmaxf(sqrtf(c2[r]), 1e-8f);
        out[(size_t)(rbase + r) * NP + col] = c0[r] / (n1 * n2);
      }
    }
  }
}

extern "C" void kernel_launch(void* const* d_in, const int* in_sizes, int n_in,
                              void* d_out, int out_size, void* d_ws, size_t ws_size,
                              hipStream_t stream) {
  const float* repres  = (const float*)d_in[0];
  const float* max_att = (const float*)d_in[1];
  const float* weight  = (const float*)d_in[2];
  float* out = (float*)d_out;

  atte_cos_mfma<<<BLOCKS, 256, 0, stream>>>(repres, max_att, weight, out);
}